// Round 3
// baseline (167.761 us; speedup 1.0000x reference)
//
#include <hip/hip_runtime.h>
#include <stdint.h>

#define HH 8192           // B*H = 16*512 strip height
#define WW 512            // width
#define WPR 8             // uint64 words per row (512/64)
#define TG22F 0.4142135623730951f
#define NROUND 8          // cap; early-exits on convergence
#define NBLK 32           // hysteresis grid (co-resident: 32 blocks << 256 CUs)

// ---- workspace layout (bytes) ----
// buf (strong, in-place) : 512 KiB @ 0
// weak bitmap            : 512 KiB @ 524288
// flags (16 ints)        : 64 B    @ 1048576
//   flags[0..7]  = per-round "grew" indicators
//   flags[8..15] = per-round grid-barrier arrive counters (single-use, no reset)

__device__ __forceinline__ float to_img(float v) {
    float t = floorf((v + 1.0f) * 0.5f * 255.0f);
    return fminf(fmaxf(t, 0.0f), 255.0f);
}

__device__ __forceinline__ int bsel(uint64_t w0, uint64_t w1, int idx) {
    return (idx < 8) ? (int)((w0 >> (idx * 8)) & 255)
                     : (int)((w1 >> ((idx - 8) * 8)) & 255);
}

// Fill all bits of runs of `w` that contain at least one bit of `s`.
__device__ __forceinline__ uint64_t runfill(uint64_t s, uint64_t w) {
    uint64_t sw = s & w;
    uint64_t up = ((sw + w) ^ w) & w;
    uint64_t rs = __brevll(sw);
    uint64_t rw = __brevll(w);
    uint64_t dn = __brevll(((rs + rw) ^ rw) & rw);
    return up | dn | sw;
}

// 64-bit shuffles via two 32-bit halves (avoid 64-bit shfl overloads).
__device__ __forceinline__ uint64_t shfl_up64(uint64_t v, int d) {
    int lo = __shfl_up((int)(uint32_t)v, d, 64);
    int hi = __shfl_up((int)(uint32_t)(v >> 32), d, 64);
    return ((uint64_t)(uint32_t)hi << 32) | (uint32_t)lo;
}
__device__ __forceinline__ uint64_t shfl_dn64(uint64_t v, int d) {
    int lo = __shfl_down((int)(uint32_t)v, d, 64);
    int hi = __shfl_down((int)(uint32_t)(v >> 32), d, 64);
    return ((uint64_t)(uint32_t)hi << 32) | (uint32_t)lo;
}

// coherent (cache-bypassing) 64-bit load/store at agent scope, no fences
__device__ __forceinline__ uint64_t cload64(const unsigned long long* p) {
    return __hip_atomic_load((const unsigned long long*)p, __ATOMIC_RELAXED,
                             __HIP_MEMORY_SCOPE_AGENT);
}
__device__ __forceinline__ void cstore64(unsigned long long* p, uint64_t v) {
    __hip_atomic_store(p, (unsigned long long)v, __ATOMIC_RELAXED,
                       __HIP_MEMORY_SCOPE_AGENT);
}

// Kernel 1: quantize + Sobel + channel argmax + NMS, all in-block.
// Block = 32 rows x 64 cols tile. Image staged with a 2-px halo (36 x 68),
// magnitude computed on a 1-px halo ring (34 x 66) by identical integer
// arithmetic as neighboring blocks' interiors (deterministic -> bitwise
// equal), out-of-strip magnitudes forced to 0 (== k_nms zero-pad semantics).
// Emits strong/weak bitmaps directly; the packed u16 array is gone.
__global__ void k_sobnms(const float* __restrict__ in,
                         unsigned long long* __restrict__ strongB,
                         unsigned long long* __restrict__ weakB,
                         int* __restrict__ flags) {
    __shared__ uint8_t  simg[3 * 36 * 80];   // image, pitch 80: byte 4 <-> col0
    __shared__ uint16_t smag[34 * 68];       // mag, [h][j]: h=0..33 <-> row -1..32, j=0..65 <-> col -1..64
    __shared__ uint8_t  sBm[32 * 8];
    __shared__ uint8_t  wBm[32 * 8];

    const int tid = threadIdx.x;
    const int row0 = (blockIdx.x >> 3) << 5;
    const int col0 = (blockIdx.x & 7) << 6;

    if (blockIdx.x == 0 && tid < 16) flags[tid] = 0;

    // ---- stage interior: 3 ch x 36 rows x 16 float4 quads ----
    for (int i = tid; i < 1728; i += 256) {
        int c = i / 576;
        int rem = i - c * 576;
        int hr = rem >> 4;
        int q  = rem & 15;
        int gy = row0 + hr - 2;
        gy = gy < 0 ? 0 : (gy >= HH ? HH - 1 : gy);
        int b = gy >> 9, h = gy & 511;
        const float4 v = *(const float4*)&in[((((b * 3 + c) << 9) + h) << 9) + col0 + (q << 2)];
        uint32_t pk = (uint32_t)(uint8_t)to_img(v.x)
                    | ((uint32_t)(uint8_t)to_img(v.y) << 8)
                    | ((uint32_t)(uint8_t)to_img(v.z) << 16)
                    | ((uint32_t)(uint8_t)to_img(v.w) << 24);
        *(uint32_t*)&simg[(c * 36 + hr) * 80 + 4 + (q << 2)] = pk;
    }
    // ---- stage edges: 3 ch x 36 rows x 4 cols (-2,-1,+64,+65) ----
    for (int i = tid; i < 432; i += 256) {
        int c = i / 144;
        int rem = i - c * 144;
        int hr = rem >> 2;
        int e = rem & 3;
        int gy = row0 + hr - 2;
        gy = gy < 0 ? 0 : (gy >= HH ? HH - 1 : gy);
        int gx = col0 + ((e == 0) ? -2 : (e == 1) ? -1 : (e == 2) ? 64 : 65);
        gx = gx < 0 ? 0 : (gx >= WW ? WW - 1 : gx);
        int b = gy >> 9, h = gy & 511;
        float v = to_img(in[((((b * 3 + c) << 9) + h) << 9) + gx]);
        int off = (e == 0) ? 2 : (e == 1) ? 3 : (e == 2) ? 68 : 69;
        simg[(c * 36 + hr) * 80 + off] = (uint8_t)v;
    }
    __syncthreads();

    const int r  = tid >> 3;          // tile row 0..31
    const int c8 = (tid & 7) << 3;    // tile col base 0..56

    // ---- interior Sobel (8 px/thread), identical math to verified kernel ----
    int bestMag[8], bgx[8], bgy[8];
    #pragma unroll
    for (int j = 0; j < 8; ++j) { bestMag[j] = -1; bgx[j] = 0; bgy[j] = 0; }

    #pragma unroll
    for (int c = 0; c < 3; ++c) {
        const uint8_t* base = &simg[(c * 36 + r + 1) * 80 + c8];
        uint64_t w00 = *(const uint64_t*)(base);
        uint64_t w01 = *(const uint64_t*)(base + 8);
        uint64_t w10 = *(const uint64_t*)(base + 80);
        uint64_t w11 = *(const uint64_t*)(base + 88);
        uint64_t w20 = *(const uint64_t*)(base + 160);
        uint64_t w21 = *(const uint64_t*)(base + 168);
        int vs[10], t0[10], t2[10];
        #pragma unroll
        for (int i = 0; i < 10; ++i) {
            int a0 = bsel(w00, w01, 3 + i);
            int a1 = bsel(w10, w11, 3 + i);
            int a2 = bsel(w20, w21, 3 + i);
            vs[i] = a0 + 2 * a1 + a2;
            t0[i] = a0; t2[i] = a2;
        }
        #pragma unroll
        for (int j = 0; j < 8; ++j) {
            int gx = vs[j + 2] - vs[j];
            int gy = (t2[j] + 2 * t2[j + 1] + t2[j + 2]) - (t0[j] + 2 * t0[j + 1] + t0[j + 2]);
            int mg = abs(gx) + abs(gy);
            if (mg > bestMag[j]) { bestMag[j] = mg; bgx[j] = gx; bgy[j] = gy; }
        }
    }
    // write interior mags into LDS
    #pragma unroll
    for (int j = 0; j < 8; ++j)
        smag[(r + 1) * 68 + (c8 + 1 + j)] = (uint16_t)bestMag[j];

    // ---- halo ring mag (196 px), same math, out-of-strip -> 0 ----
    if (tid < 196) {
        int h, j;
        if (tid < 66)       { h = 0;        j = tid; }
        else if (tid < 132) { h = 33;       j = tid - 66; }
        else if (tid < 164) { h = tid - 131; j = 0; }    // 1..32
        else                { h = tid - 163; j = 65; }   // 1..32
        int gy = row0 + h - 1, gx = col0 + j - 1;
        int mg = 0;
        if (gy >= 0 && gy < HH && gx >= 0 && gx < WW) {
            #pragma unroll
            for (int c = 0; c < 3; ++c) {
                const uint8_t* p = &simg[(c * 36 + h) * 80 + (j + 2)];
                int a00 = p[0],   a01 = p[1],   a02 = p[2];
                int a10 = p[80],                a12 = p[82];
                int a20 = p[160], a21 = p[161], a22 = p[162];
                int gxx = (a02 + 2 * a12 + a22) - (a00 + 2 * a10 + a20);
                int gyy = (a20 + 2 * a21 + a22) - (a00 + 2 * a01 + a02);
                int m = abs(gxx) + abs(gyy);
                if (m > mg) mg = m;
            }
        }
        smag[h * 68 + j] = (uint16_t)mg;
    }
    __syncthreads();

    // ---- NMS + thresholds -> byte masks ----
    uint32_t sbyte = 0, wbyte = 0;
    #pragma unroll
    for (int j = 0; j < 8; ++j) {
        int mag = bestMag[j];
        float axf = (float)abs(bgx[j]);
        float ayf = (float)abs(bgy[j]);
        int dir;
        if (ayf < TG22F * axf)      dir = 0;
        else if (ayf * TG22F > axf) dir = 1;
        else                        dir = (bgx[j] * bgy[j] >= 0) ? 2 : 3;
        int d1y = (dir == 0) ? 0 : -1;
        int d1x = (dir == 0) ? -1 : (dir == 1) ? 0 : (dir == 2) ? -1 : 1;
        int hh0 = r + 1, cc0 = c8 + 1 + j;
        int n1 = smag[(hh0 + d1y) * 68 + (cc0 + d1x)];
        int n2 = smag[(hh0 - d1y) * 68 + (cc0 - d1x)];
        bool keep = (mag > n1) && (mag >= n2);
        if (keep && mag > 200) sbyte |= 1u << j;
        if (keep && mag > 100) wbyte |= 1u << j;
    }
    sBm[r * 8 + (tid & 7)] = (uint8_t)sbyte;
    wBm[r * 8 + (tid & 7)] = (uint8_t)wbyte;
    __syncthreads();

    if (tid < 32) {
        uint64_t wS = *(const uint64_t*)&sBm[tid * 8];
        strongB[(row0 + tid) * WPR + (col0 >> 6)] = wS;
    } else if (tid >= 64 && tid < 96) {
        int t = tid - 64;
        uint64_t wW = *(const uint64_t*)&wBm[t * 8];
        weakB[(row0 + t) * WPR + (col0 >> 6)] = wW;
    }
}

// Kernel 2: ALL hysteresis rounds in ONE kernel + direct output expansion.
// Each wave owns a 64x512 band in registers. Between rounds only boundary
// rows + flags are exchanged as RELAXED agent-scope atomics (cache-bypassing,
// no wbl2/inv maintenance); ordering store->counter comes from the vmcnt(0)
// drain before s_barrier. After convergence each wave expands its final band
// bits -> {-1,+1} float4 and streams the (16,3,512,512) output directly
// (state is already in registers; k_out and the final buf writeback are gone).
__global__ void __launch_bounds__(256) k_hyst(
        const unsigned long long* __restrict__ weakB,
        unsigned long long* __restrict__ buf,
        int* __restrict__ flags,
        float* __restrict__ out)
{
    const int lane = threadIdx.x & 63;
    const int wave = (blockIdx.x << 2) + (threadIdx.x >> 6);   // 0..127
    const int base = ((wave << 6) + lane) * WPR;               // own row

    uint64_t own[8], wk[8];
    #pragma unroll
    for (int k = 0; k < 8; ++k) { wk[k] = weakB[base + k]; own[k] = buf[base + k]; }

    uint64_t hspu[8], hspd[8];
    #pragma unroll
    for (int k = 0; k < 8; ++k) { hspu[k] = 0; hspd[k] = 0; }

    auto load_halo = [&]() {
        uint64_t h[8];
        if (lane == 0 && wave > 0) {
            #pragma unroll
            for (int k = 0; k < 8; ++k) h[k] = cload64(&buf[base - WPR + k]);
            #pragma unroll
            for (int k = 0; k < 8; ++k) {
                uint64_t a = h[k] | (h[k] << 1) | (h[k] >> 1);
                if (k > 0) a |= h[k - 1] >> 63;
                if (k < 7) a |= h[k + 1] << 63;
                hspu[k] = a;
            }
        }
        if (lane == 63 && wave < 127) {
            #pragma unroll
            for (int k = 0; k < 8; ++k) h[k] = cload64(&buf[base + WPR + k]);
            #pragma unroll
            for (int k = 0; k < 8; ++k) {
                uint64_t a = h[k] | (h[k] << 1) | (h[k] >> 1);
                if (k > 0) a |= h[k - 1] >> 63;
                if (k < 7) a |= h[k + 1] << 63;
                hspd[k] = a;
            }
        }
    };
    load_halo();

    for (int r = 0; r < NROUND; ++r) {
        // ---- converge this band with current halos ----
        bool grew = false;
        for (;;) {
            uint64_t sp[8];
            #pragma unroll
            for (int k = 0; k < 8; ++k) {
                uint64_t h = own[k] | (own[k] << 1) | (own[k] >> 1);
                if (k > 0) h |= own[k - 1] >> 63;
                if (k < 7) h |= own[k + 1] << 63;
                sp[k] = h;
            }
            uint64_t su[8], sd[8];
            #pragma unroll
            for (int k = 0; k < 8; ++k) {
                su[k] = shfl_up64(sp[k], 1);
                sd[k] = shfl_dn64(sp[k], 1);
            }
            if (lane == 0) {
                #pragma unroll
                for (int k = 0; k < 8; ++k) su[k] = hspu[k];
            }
            if (lane == 63) {
                #pragma unroll
                for (int k = 0; k < 8; ++k) sd[k] = hspd[k];
            }
            uint32_t ch = 0;
            #pragma unroll
            for (int k = 0; k < 8; ++k) {
                uint64_t acc = sp[k] | su[k] | sd[k];
                uint64_t nv = runfill(own[k] | (acc & wk[k]), wk[k]);
                ch |= (uint32_t)(nv != own[k]);
                own[k] = nv;
            }
            if (ch) grew = true;
            if (__ballot(ch ? 1 : 0) == 0ull) break;   // wave-uniform
        }

        // ---- publish growth flag + boundary rows (coherent, relaxed) ----
        if (grew && lane == 0)
            __hip_atomic_store(&flags[r], 1, __ATOMIC_RELAXED, __HIP_MEMORY_SCOPE_AGENT);
        if (lane == 0 || lane == 63) {
            #pragma unroll
            for (int k = 0; k < 8; ++k) cstore64(&buf[base + k], own[k]);
        }
        __syncthreads();
        if (threadIdx.x == 0) {
            __hip_atomic_fetch_add(&flags[8 + r], 1, __ATOMIC_RELAXED, __HIP_MEMORY_SCOPE_AGENT);
            while (__hip_atomic_load(&flags[8 + r], __ATOMIC_RELAXED, __HIP_MEMORY_SCOPE_AGENT) < NBLK)
                __builtin_amdgcn_s_sleep(2);
        }
        __syncthreads();

        if (__hip_atomic_load(&flags[r], __ATOMIC_RELAXED, __HIP_MEMORY_SCOPE_AGENT) == 0)
            break;
        if (r + 1 < NROUND) load_halo();
    }

    // ---- expand final band bits -> output, 3 channels, float4 stores ----
    const int y = (wave << 6) + lane;
    const int b = y >> 9, h = y & 511;
    const int obase = ((b * 3) << 18) + (h << 9);
    #pragma unroll
    for (int k = 0; k < 8; ++k) {
        uint64_t wv = own[k];
        #pragma unroll
        for (int q = 0; q < 16; ++q) {
            int x = (k << 6) + (q << 2);
            int sh = q << 2;
            float4 v;
            v.x = ((wv >> (sh + 0)) & 1ull) ? 1.0f : -1.0f;
            v.y = ((wv >> (sh + 1)) & 1ull) ? 1.0f : -1.0f;
            v.z = ((wv >> (sh + 2)) & 1ull) ? 1.0f : -1.0f;
            v.w = ((wv >> (sh + 3)) & 1ull) ? 1.0f : -1.0f;
            *(float4*)&out[obase + x] = v;
            *(float4*)&out[obase + (1 << 18) + x] = v;
            *(float4*)&out[obase + (2 << 18) + x] = v;
        }
    }
}

extern "C" void kernel_launch(void* const* d_in, const int* in_sizes, int n_in,
                              void* d_out, int out_size, void* d_ws, size_t ws_size,
                              hipStream_t stream) {
    const float* x = (const float*)d_in[0];
    float* out = (float*)d_out;
    char* ws = (char*)d_ws;

    unsigned long long* buf   = (unsigned long long*)(ws);
    unsigned long long* weakB = (unsigned long long*)(ws + 524288);
    int* flags                = (int*)(ws + 1048576);

    k_sobnms<<<2048, 256, 0, stream>>>(x, buf, weakB, flags);
    k_hyst<<<NBLK, 256, 0, stream>>>(weakB, buf, flags, out);
}

// Round 5
// 122.927 us; speedup vs baseline: 1.3647x; 1.3647x over previous
//
#include <hip/hip_runtime.h>
#include <stdint.h>

#define HH 8192           // B*H = 16*512 strip height
#define WW 512            // width
#define WPR 8             // uint64 words per row (512/64)
#define TG22F 0.4142135623730951f
#define NROUND 8          // cap; early-exits on convergence
#define NBLK 32           // hysteresis grid (co-resident: 32 blocks << 256 CUs)

// ---- workspace layout (bytes) ----
// packed u16 mag|dir<<12 : 8 MiB   @ 0
// buf (strong, in-place) : 512 KiB @ 8388608
// weak bitmap            : 512 KiB @ 8912896
// flags (16 ints)        : 64 B    @ 9437184
//   flags[0..7]  = per-round "grew" indicators
//   flags[8..15] = per-round grid-barrier arrive counters (single-use, no reset)

__device__ __forceinline__ float to_img(float v) {
    float t = floorf((v + 1.0f) * 0.5f * 255.0f);
    return fminf(fmaxf(t, 0.0f), 255.0f);
}

__device__ __forceinline__ int bsel(uint64_t w0, uint64_t w1, int idx) {
    return (idx < 8) ? (int)((w0 >> (idx * 8)) & 255)
                     : (int)((w1 >> ((idx - 8) * 8)) & 255);
}

// Fill all bits of runs of `w` that contain at least one bit of `s`.
__device__ __forceinline__ uint64_t runfill(uint64_t s, uint64_t w) {
    uint64_t sw = s & w;
    uint64_t up = ((sw + w) ^ w) & w;
    uint64_t rs = __brevll(sw);
    uint64_t rw = __brevll(w);
    uint64_t dn = __brevll(((rs + rw) ^ rw) & rw);
    return up | dn | sw;
}

// 64-bit shuffles via two 32-bit halves (avoid 64-bit shfl overloads).
__device__ __forceinline__ uint64_t shfl_up64(uint64_t v, int d) {
    int lo = __shfl_up((int)(uint32_t)v, d, 64);
    int hi = __shfl_up((int)(uint32_t)(v >> 32), d, 64);
    return ((uint64_t)(uint32_t)hi << 32) | (uint32_t)lo;
}
__device__ __forceinline__ uint64_t shfl_dn64(uint64_t v, int d) {
    int lo = __shfl_down((int)(uint32_t)v, d, 64);
    int hi = __shfl_down((int)(uint32_t)(v >> 32), d, 64);
    return ((uint64_t)(uint32_t)hi << 32) | (uint32_t)lo;
}

// coherent (cache-bypassing) 64-bit load/store at agent scope, no fences
__device__ __forceinline__ uint64_t cload64(const unsigned long long* p) {
    return __hip_atomic_load((const unsigned long long*)p, __ATOMIC_RELAXED,
                             __HIP_MEMORY_SCOPE_AGENT);
}
__device__ __forceinline__ void cstore64(unsigned long long* p, uint64_t v) {
    __hip_atomic_store(p, (unsigned long long)v, __ATOMIC_RELAXED,
                       __HIP_MEMORY_SCOPE_AGENT);
}

// Kernel 1: quantize + Sobel (replicate pad on strip) + channel argmax + dir.
// (verbatim verified version)
__global__ void k_sobel(const float* __restrict__ in, uint16_t* __restrict__ packed) {
    __shared__ uint8_t simg[3 * 34 * 72];
    const int tid = threadIdx.x;
    const int row0 = (blockIdx.x >> 3) << 5;
    const int col0 = (blockIdx.x & 7) << 6;

    for (int i = tid; i < 1632; i += 256) {
        int c = i / 544;
        int rem = i - c * 544;
        int hr = rem >> 4;
        int q = rem & 15;
        int gy = row0 + hr - 1;
        gy = gy < 0 ? 0 : (gy >= HH ? HH - 1 : gy);
        int b = gy >> 9, h = gy & 511;
        const float4 v = *(const float4*)&in[((((b * 3 + c) << 9) + h) << 9) + col0 + (q << 2)];
        uint32_t pk = (uint32_t)(uint8_t)to_img(v.x)
                    | ((uint32_t)(uint8_t)to_img(v.y) << 8)
                    | ((uint32_t)(uint8_t)to_img(v.z) << 16)
                    | ((uint32_t)(uint8_t)to_img(v.w) << 24);
        *(uint32_t*)&simg[(c * 34 + hr) * 72 + 4 + (q << 2)] = pk;
    }
    for (int i = tid; i < 204; i += 256) {
        int c = i / 68;
        int rem = i - c * 68;
        int hr = rem >> 1;
        int side = rem & 1;
        int gy = row0 + hr - 1;
        gy = gy < 0 ? 0 : (gy >= HH ? HH - 1 : gy);
        int gc = side ? col0 + 64 : col0 - 1;
        gc = gc < 0 ? 0 : (gc >= WW ? WW - 1 : gc);
        int b = gy >> 9, h = gy & 511;
        float v = to_img(in[((((b * 3 + c) << 9) + h) << 9) + gc]);
        simg[(c * 34 + hr) * 72 + (side ? 68 : 3)] = (uint8_t)v;
    }
    __syncthreads();

    const int r = tid >> 3;
    const int c8 = (tid & 7) << 3;

    int bestMag[8], bgx[8], bgy[8];
    #pragma unroll
    for (int j = 0; j < 8; ++j) { bestMag[j] = -1; bgx[j] = 0; bgy[j] = 0; }

    #pragma unroll
    for (int c = 0; c < 3; ++c) {
        const uint8_t* base = &simg[(c * 34 + r) * 72 + c8];
        uint64_t w00 = *(const uint64_t*)(base);
        uint64_t w01 = *(const uint64_t*)(base + 8);
        uint64_t w10 = *(const uint64_t*)(base + 72);
        uint64_t w11 = *(const uint64_t*)(base + 80);
        uint64_t w20 = *(const uint64_t*)(base + 144);
        uint64_t w21 = *(const uint64_t*)(base + 152);
        int vs[10], t0[10], t2[10];
        #pragma unroll
        for (int i = 0; i < 10; ++i) {
            int a0 = bsel(w00, w01, 3 + i);
            int a1 = bsel(w10, w11, 3 + i);
            int a2 = bsel(w20, w21, 3 + i);
            vs[i] = a0 + 2 * a1 + a2;
            t0[i] = a0; t2[i] = a2;
        }
        #pragma unroll
        for (int j = 0; j < 8; ++j) {
            int gx = vs[j + 2] - vs[j];
            int gy = (t2[j] + 2 * t2[j + 1] + t2[j + 2]) - (t0[j] + 2 * t0[j + 1] + t0[j + 2]);
            int mg = abs(gx) + abs(gy);
            if (mg > bestMag[j]) { bestMag[j] = mg; bgx[j] = gx; bgy[j] = gy; }
        }
    }

    uint32_t res[4];
    #pragma unroll
    for (int jj = 0; jj < 4; ++jj) {
        uint32_t pair = 0;
        #pragma unroll
        for (int s = 0; s < 2; ++s) {
            int j = jj * 2 + s;
            float axf = (float)abs(bgx[j]);
            float ayf = (float)abs(bgy[j]);
            int dir;
            if (ayf < TG22F * axf)      dir = 0;
            else if (ayf * TG22F > axf) dir = 1;
            else                        dir = (bgx[j] * bgy[j] >= 0) ? 2 : 3;
            uint32_t val = (uint32_t)(bestMag[j] | (dir << 12));
            pair |= val << (s * 16);
        }
        res[jj] = pair;
    }
    int y = row0 + r;
    *(uint4*)&packed[y * WW + col0 + c8] = *(uint4*)res;
}

// extract mag (12 bits) of px idx (0..7, compile-time) from a row quad (lo,hi)
#define MEXT(lo, hi, idx) ((int)((((idx) < 4 ? ((lo) >> (16 * (idx))) \
                                             : ((hi) >> (16 * ((idx) - 4))))) & 0xFFF))

// Kernel 2: NMS, one wave per image row, 8 px per lane.
// Three coalesced 16B row loads per lane (own/up/down); left/right neighbor
// mags via intra-wave shuffles (a row = exactly one wave, so no cross-wave
// edges). Out-of-strip rows and x<0 / x>=WW neighbors read as 0 -- identical
// semantics to the verified per-pixel k_nms. Bitmaps packed via shuffles,
// no LDS, no barrier. Also zeroes flags (block 0).
__global__ void k_nms(const uint16_t* __restrict__ packed,
                      unsigned long long* __restrict__ strongB,
                      unsigned long long* __restrict__ weakB,
                      int* __restrict__ flags) {
    if (blockIdx.x == 0 && threadIdx.x < 16) flags[threadIdx.x] = 0;
    const int lane = threadIdx.x & 63;
    const int w = threadIdx.x >> 6;
    const int y = (blockIdx.x << 2) + w;

    uint4 q = *(const uint4*)&packed[y * WW + (lane << 3)];
    uint64_t oLo = ((uint64_t)q.y << 32) | q.x;
    uint64_t oHi = ((uint64_t)q.w << 32) | q.z;
    uint64_t uLo = 0, uHi = 0, dLo = 0, dHi = 0;
    if (y > 0) {
        uint4 qu = *(const uint4*)&packed[(y - 1) * WW + (lane << 3)];
        uLo = ((uint64_t)qu.y << 32) | qu.x;
        uHi = ((uint64_t)qu.w << 32) | qu.z;
    }
    if (y < HH - 1) {
        uint4 qd = *(const uint4*)&packed[(y + 1) * WW + (lane << 3)];
        dLo = ((uint64_t)qd.y << 32) | qd.x;
        dHi = ((uint64_t)qd.w << 32) | qd.z;
    }

    // neighbor px across lane boundary (mag only); x<0 / x>=WW -> 0
    int oL = __shfl_up((int)((oHi >> 48) & 0xFFF), 1, 64); if (lane == 0) oL = 0;
    int uL = __shfl_up((int)((uHi >> 48) & 0xFFF), 1, 64); if (lane == 0) uL = 0;
    int dL = __shfl_up((int)((dHi >> 48) & 0xFFF), 1, 64); if (lane == 0) dL = 0;
    int oR = __shfl_down((int)(oLo & 0xFFF), 1, 64); if (lane == 63) oR = 0;
    int uR = __shfl_down((int)(uLo & 0xFFF), 1, 64); if (lane == 63) uR = 0;
    int dR = __shfl_down((int)(dLo & 0xFFF), 1, 64); if (lane == 63) dR = 0;

    uint32_t sb = 0, wb = 0;
    #pragma unroll
    for (int i = 0; i < 8; ++i) {
        int raw = (int)(((i < 4 ? (oLo >> (16 * i)) : (oHi >> (16 * (i - 4))))) & 0xFFFF);
        int m = raw & 0xFFF;
        int dir = raw >> 12;
        int Om1 = (i == 0) ? oL : MEXT(oLo, oHi, (i == 0 ? 0 : i - 1));
        int Op1 = (i == 7) ? oR : MEXT(oLo, oHi, (i == 7 ? 7 : i + 1));
        int Ui  = MEXT(uLo, uHi, i);
        int Um1 = (i == 0) ? uL : MEXT(uLo, uHi, (i == 0 ? 0 : i - 1));
        int Up1 = (i == 7) ? uR : MEXT(uLo, uHi, (i == 7 ? 7 : i + 1));
        int Di  = MEXT(dLo, dHi, i);
        int Dm1 = (i == 0) ? dL : MEXT(dLo, dHi, (i == 0 ? 0 : i - 1));
        int Dp1 = (i == 7) ? dR : MEXT(dLo, dHi, (i == 7 ? 7 : i + 1));
        // dir0:(0,-1) dir1:(-1,0) dir2:(-1,-1) dir3:(-1,+1); n1=+d1, n2=-d1
        int n1 = (dir == 0) ? Om1 : (dir == 1) ? Ui : (dir == 2) ? Um1 : Up1;
        int n2 = (dir == 0) ? Op1 : (dir == 1) ? Di : (dir == 2) ? Dp1 : Dm1;
        bool keep = (m > n1) && (m >= n2);
        if (keep && m > 200) sb |= 1u << i;
        if (keep && m > 100) wb |= 1u << i;
    }

    // pack 64 lanes x 8 bits -> 8 u64 words per row via shuffles
    const int src = (lane & 7) << 3;
    uint64_t wordS = 0, wordW = 0;
    #pragma unroll
    for (int i = 0; i < 8; ++i) {
        wordS |= (uint64_t)(uint32_t)__shfl((int)sb, src + i, 64) << (i * 8);
        wordW |= (uint64_t)(uint32_t)__shfl((int)wb, src + i, 64) << (i * 8);
    }
    if (lane < 8)       strongB[y * WPR + lane] = wordS;
    else if (lane < 16) weakB[y * WPR + (lane - 8)] = wordW;
}

// Kernel 3: ALL hysteresis rounds in ONE kernel (round-2 verified version).
// Relaxed agent-scope halo exchange, spin grid barrier, final writeback.
__global__ void __launch_bounds__(256) k_hyst(
        const unsigned long long* __restrict__ weakB,
        unsigned long long* __restrict__ buf,
        int* __restrict__ flags)
{
    const int lane = threadIdx.x & 63;
    const int wave = (blockIdx.x << 2) + (threadIdx.x >> 6);   // 0..127
    const int base = ((wave << 6) + lane) * WPR;               // own row

    uint64_t own[8], wk[8];
    #pragma unroll
    for (int k = 0; k < 8; ++k) { wk[k] = weakB[base + k]; own[k] = buf[base + k]; }

    uint64_t hspu[8], hspd[8];
    #pragma unroll
    for (int k = 0; k < 8; ++k) { hspu[k] = 0; hspd[k] = 0; }

    auto load_halo = [&]() {
        uint64_t h[8];
        if (lane == 0 && wave > 0) {
            #pragma unroll
            for (int k = 0; k < 8; ++k) h[k] = cload64(&buf[base - WPR + k]);
            #pragma unroll
            for (int k = 0; k < 8; ++k) {
                uint64_t a = h[k] | (h[k] << 1) | (h[k] >> 1);
                if (k > 0) a |= h[k - 1] >> 63;
                if (k < 7) a |= h[k + 1] << 63;
                hspu[k] = a;
            }
        }
        if (lane == 63 && wave < 127) {
            #pragma unroll
            for (int k = 0; k < 8; ++k) h[k] = cload64(&buf[base + WPR + k]);
            #pragma unroll
            for (int k = 0; k < 8; ++k) {
                uint64_t a = h[k] | (h[k] << 1) | (h[k] >> 1);
                if (k > 0) a |= h[k - 1] >> 63;
                if (k < 7) a |= h[k + 1] << 63;
                hspd[k] = a;
            }
        }
    };
    load_halo();

    bool grewAny = false;
    for (int r = 0; r < NROUND; ++r) {
        bool grew = false;
        for (;;) {
            uint64_t sp[8];
            #pragma unroll
            for (int k = 0; k < 8; ++k) {
                uint64_t h = own[k] | (own[k] << 1) | (own[k] >> 1);
                if (k > 0) h |= own[k - 1] >> 63;
                if (k < 7) h |= own[k + 1] << 63;
                sp[k] = h;
            }
            uint64_t su[8], sd[8];
            #pragma unroll
            for (int k = 0; k < 8; ++k) {
                su[k] = shfl_up64(sp[k], 1);
                sd[k] = shfl_dn64(sp[k], 1);
            }
            if (lane == 0) {
                #pragma unroll
                for (int k = 0; k < 8; ++k) su[k] = hspu[k];
            }
            if (lane == 63) {
                #pragma unroll
                for (int k = 0; k < 8; ++k) sd[k] = hspd[k];
            }
            uint32_t ch = 0;
            #pragma unroll
            for (int k = 0; k < 8; ++k) {
                uint64_t acc = sp[k] | su[k] | sd[k];
                uint64_t nv = runfill(own[k] | (acc & wk[k]), wk[k]);
                ch |= (uint32_t)(nv != own[k]);
                own[k] = nv;
            }
            if (ch) grew = true;
            if (__ballot(ch ? 1 : 0) == 0ull) break;   // wave-uniform
        }
        grewAny |= grew;

        if (grew && lane == 0)
            __hip_atomic_store(&flags[r], 1, __ATOMIC_RELAXED, __HIP_MEMORY_SCOPE_AGENT);
        if (lane == 0 || lane == 63) {
            #pragma unroll
            for (int k = 0; k < 8; ++k) cstore64(&buf[base + k], own[k]);
        }
        __syncthreads();
        if (threadIdx.x == 0) {
            __hip_atomic_fetch_add(&flags[8 + r], 1, __ATOMIC_RELAXED, __HIP_MEMORY_SCOPE_AGENT);
            while (__hip_atomic_load(&flags[8 + r], __ATOMIC_RELAXED, __HIP_MEMORY_SCOPE_AGENT) < NBLK)
                __builtin_amdgcn_s_sleep(2);
        }
        __syncthreads();

        if (__hip_atomic_load(&flags[r], __ATOMIC_RELAXED, __HIP_MEMORY_SCOPE_AGENT) == 0)
            break;
        if (r + 1 < NROUND) load_halo();
    }

    if (__ballot(grewAny ? 1 : 0) != 0ull) {
        #pragma unroll
        for (int k = 0; k < 8; ++k) buf[base + k] = own[k];
    }
}

// Kernel 4: expand bitmap -> (16,3,512,512) f32 output in {-1,+1}, float4.
__global__ void k_out(const unsigned long long* __restrict__ result, float* __restrict__ out) {
    int t = blockIdx.x * blockDim.x + threadIdx.x;
    int b = t >> 16;
    int r = t & 65535;
    int h = r >> 7;
    int w = (r & 127) << 2;
    int y = (b << 9) + h;
    unsigned long long word = result[y * WPR + (w >> 6)];
    int sh = w & 63;
    float4 v;
    v.x = ((word >> (sh + 0)) & 1ull) ? 1.0f : -1.0f;
    v.y = ((word >> (sh + 1)) & 1ull) ? 1.0f : -1.0f;
    v.z = ((word >> (sh + 2)) & 1ull) ? 1.0f : -1.0f;
    v.w = ((word >> (sh + 3)) & 1ull) ? 1.0f : -1.0f;
    int base = (b * 3) << 18;
    int off = (h << 9) + w;
    *(float4*)&out[base + off] = v;
    *(float4*)&out[base + 262144 + off] = v;
    *(float4*)&out[base + 524288 + off] = v;
}

extern "C" void kernel_launch(void* const* d_in, const int* in_sizes, int n_in,
                              void* d_out, int out_size, void* d_ws, size_t ws_size,
                              hipStream_t stream) {
    const float* x = (const float*)d_in[0];
    float* out = (float*)d_out;
    char* ws = (char*)d_ws;

    uint16_t* packed          = (uint16_t*)(ws);
    unsigned long long* buf   = (unsigned long long*)(ws + 8388608);
    unsigned long long* weakB = (unsigned long long*)(ws + 8912896);
    int* flags                = (int*)(ws + 9437184);

    k_sobel<<<2048, 256, 0, stream>>>(x, packed);
    k_nms<<<2048, 256, 0, stream>>>(packed, buf, weakB, flags);
    k_hyst<<<NBLK, 256, 0, stream>>>(weakB, buf, flags);
    k_out<<<4096, 256, 0, stream>>>(buf, out);
}